// Round 1
// baseline (4063.059 us; speedup 1.0000x reference)
//
#include <hip/hip_runtime.h>
#include <hip/hip_bf16.h>

// GIN 4-layer forward. f32 baseline, CSR aggregation, chunked fused GEMMs.
// ws usage ~160MB: z0, chunk, z2 (z2 doubles as h), CSR arrays, stats, pool.

#define WG_GEMM 256
#define BM 128
#define BNC 128
#define BK 32

__device__ __forceinline__ float selu_f(float x){
    const float sc = 1.0507009873554805f, al = 1.6732632423543772f;
    return x > 0.f ? sc * x : sc * al * expm1f(x);
}

// ---------------- CSR build ----------------
__global__ void count_kernel(const int* __restrict__ dst, int* __restrict__ counts, int E){
    int e = blockIdx.x * 256 + threadIdx.x;
    if (e < E) atomicAdd(&counts[dst[e]], 1);
}

__global__ void gcount_kernel(const int* __restrict__ batch, int* __restrict__ gcount, int N){
    int i = blockIdx.x * 256 + threadIdx.x;
    if (i < N) atomicAdd(&gcount[batch[i]], 1);
}

__global__ void cnt_final_kernel(const int* __restrict__ gcount, float* __restrict__ cnt){
    int g = threadIdx.x;
    cnt[g] = fmaxf((float)gcount[g], 1.f);
}

__global__ __launch_bounds__(1024) void scan_kernel(const int* __restrict__ counts,
                                                    int* __restrict__ row_ptr, int N){
    __shared__ int wsum[16];
    __shared__ int wpre[16];
    __shared__ int s_total;
    __shared__ int s_running;
    int tid = threadIdx.x;
    int lane = tid & 63, wid = tid >> 6;
    if (tid == 0) s_running = 0;
    __syncthreads();
    for (int base = 0; base < N; base += 4096){
        int idx0 = base + tid * 4;
        int v[4];
        #pragma unroll
        for (int j = 0; j < 4; j++) v[j] = (idx0 + j < N) ? counts[idx0 + j] : 0;
        int tsum = v[0] + v[1] + v[2] + v[3];
        int x = tsum;
        #pragma unroll
        for (int off = 1; off < 64; off <<= 1){
            int y = __shfl_up(x, off, 64);
            if (lane >= off) x += y;
        }
        if (lane == 63) wsum[wid] = x;
        __syncthreads();
        if (wid == 0 && lane < 16){
            int w = wsum[lane];
            int xx = w;
            #pragma unroll
            for (int off = 1; off < 16; off <<= 1){
                int y = __shfl_up(xx, off, 64);
                if (lane >= off) xx += y;
            }
            wpre[lane] = xx - w;
            if (lane == 15) s_total = xx;
        }
        __syncthreads();
        int run = s_running + wpre[wid] + (x - tsum);
        #pragma unroll
        for (int j = 0; j < 4; j++){
            if (idx0 + j < N) row_ptr[idx0 + j] = run;
            run += v[j];
        }
        __syncthreads();
        if (tid == 0) s_running += s_total;
        __syncthreads();
    }
    if (tid == 0) row_ptr[N] = s_running;
}

__global__ void fill_kernel(const int* __restrict__ ei, const int* __restrict__ row_ptr,
                            int* __restrict__ fill, int* __restrict__ colv, int E){
    int e = blockIdx.x * 256 + threadIdx.x;
    if (e < E){
        int s = ei[e];
        int d = ei[E + e];
        int pos = atomicAdd(&fill[d], 1);
        colv[row_ptr[d] + pos] = s;
    }
}

// ---------------- GIN aggregation: z0 = h + sum_{j->i} h_j ----------------
__global__ void agg_kernel(const float* __restrict__ h, const int* __restrict__ row_ptr,
                           const int* __restrict__ colv, float* __restrict__ z0, int N){
    int i = blockIdx.x;
    int c = threadIdx.x;
    int p0 = row_ptr[i], p1 = row_ptr[i + 1];
    float acc = h[(size_t)i * 128 + c];
    for (int p = p0; p < p1; p++){
        int s = colv[p];
        acc += h[(size_t)s * 128 + c];
    }
    z0[(size_t)i * 128 + c] = acc;
}

// ---------------- GEMM1: chunk = z0 @ W1chunk^T  (B row-major [128][128]) ----------------
__global__ __launch_bounds__(WG_GEMM) void gemm1_kernel(
    const float* __restrict__ A, const float* __restrict__ B,
    float* __restrict__ C, int N)
{
    __shared__ float As[BK][BM + 4];
    __shared__ float Bs[BK][BNC + 4];
    int tid = threadIdx.x;
    int tx = tid & 15, ty = tid >> 4;
    int m0 = blockIdx.x * BM;
    float acc[8][8];
    #pragma unroll
    for (int i = 0; i < 8; i++)
        #pragma unroll
        for (int j = 0; j < 8; j++) acc[i][j] = 0.f;

    for (int kk = 0; kk < 128; kk += BK){
        __syncthreads();
        #pragma unroll
        for (int p = 0; p < 4; p++){
            int f = p * 256 + tid;
            int r = f >> 3;
            int c4 = (f & 7) * 4;
            int row = m0 + r;
            float4 v = make_float4(0.f, 0.f, 0.f, 0.f);
            if (row < N) v = *reinterpret_cast<const float4*>(&A[(size_t)row * 128 + kk + c4]);
            As[c4 + 0][r] = v.x; As[c4 + 1][r] = v.y; As[c4 + 2][r] = v.z; As[c4 + 3][r] = v.w;
        }
        #pragma unroll
        for (int p = 0; p < 4; p++){
            int f = p * 256 + tid;
            int j = f >> 3;
            int c4 = (f & 7) * 4;
            float4 v = *reinterpret_cast<const float4*>(&B[(size_t)j * 128 + kk + c4]);
            Bs[c4 + 0][j] = v.x; Bs[c4 + 1][j] = v.y; Bs[c4 + 2][j] = v.z; Bs[c4 + 3][j] = v.w;
        }
        __syncthreads();
        #pragma unroll
        for (int k = 0; k < BK; k++){
            float a[8], b[8];
            #pragma unroll
            for (int i = 0; i < 8; i++) a[i] = As[k][ty * 8 + i];
            #pragma unroll
            for (int j = 0; j < 8; j++) b[j] = Bs[k][tx * 8 + j];
            #pragma unroll
            for (int i = 0; i < 8; i++)
                #pragma unroll
                for (int j = 0; j < 8; j++)
                    acc[i][j] = fmaf(a[i], b[j], acc[i][j]);
        }
    }
    #pragma unroll
    for (int i = 0; i < 8; i++){
        int row = m0 + ty * 8 + i;
        if (row < N){
            #pragma unroll
            for (int j = 0; j < 8; j++)
                C[(size_t)row * 128 + tx * 8 + j] = acc[i][j];
        }
    }
}

// ---------------- BN column stats over chunk ----------------
__global__ void bn_stats_kernel(const float* __restrict__ chunk, float* __restrict__ bsum,
                                float* __restrict__ bsq, int N){
    int c = threadIdx.x;
    int base = blockIdx.x * 128;
    int end = min(128, N - base);
    float s = 0.f, q = 0.f;
    for (int r = 0; r < end; r++){
        float v = chunk[(size_t)(base + r) * 128 + c];
        s += v; q += v * v;
    }
    atomicAdd(&bsum[c], s);
    atomicAdd(&bsq[c], q);
}

__global__ void bn_final_kernel(float* __restrict__ bsum, float* __restrict__ bsq,
                                const float* __restrict__ bng, const float* __restrict__ bnb,
                                float* __restrict__ scale, float* __restrict__ shift,
                                int l, int c0, int N){
    int c = threadIdx.x;
    float n = (float)N;
    float mu = bsum[c] / n;
    float var = bsq[c] / n - mu * mu;
    float inv = rsqrtf(var + 1e-5f);
    float sc = bng[l * 512 + c0 + c] * inv;
    scale[c] = sc;
    shift[c] = bnb[l * 512 + c0 + c] - mu * sc;
    bsum[c] = 0.f;
    bsq[c] = 0.f;
}

// -------- GEMM2: z2 (+)= selu(bn(chunk)) @ W2chunk^T   (B row-major [128][ldb]) --------
__global__ __launch_bounds__(WG_GEMM) void gemm2_kernel(
    const float* __restrict__ A, const float* __restrict__ Bw, int ldb,
    float* __restrict__ Cz2, const float* __restrict__ bscale, const float* __restrict__ bshift,
    const float* __restrict__ b2l, int first, int N)
{
    __shared__ float As[BK][BM + 4];
    __shared__ float Bs[BK][BNC + 4];
    __shared__ float s_sc[128], s_sh[128];
    int tid = threadIdx.x;
    if (tid < 128){ s_sc[tid] = bscale[tid]; s_sh[tid] = bshift[tid]; }
    int tx = tid & 15, ty = tid >> 4;
    int m0 = blockIdx.x * BM;
    float acc[8][8];
    #pragma unroll
    for (int i = 0; i < 8; i++)
        #pragma unroll
        for (int j = 0; j < 8; j++) acc[i][j] = 0.f;

    for (int kk = 0; kk < 128; kk += BK){
        __syncthreads();
        #pragma unroll
        for (int p = 0; p < 4; p++){
            int f = p * 256 + tid;
            int r = f >> 3;
            int c4 = (f & 7) * 4;
            int row = m0 + r;
            float4 v = make_float4(0.f, 0.f, 0.f, 0.f);
            if (row < N) v = *reinterpret_cast<const float4*>(&A[(size_t)row * 128 + kk + c4]);
            float vv[4] = {v.x, v.y, v.z, v.w};
            #pragma unroll
            for (int j = 0; j < 4; j++){
                int k = kk + c4 + j;
                float t = fmaf(vv[j], s_sc[k], s_sh[k]);
                vv[j] = selu_f(t);
            }
            As[c4 + 0][r] = vv[0]; As[c4 + 1][r] = vv[1]; As[c4 + 2][r] = vv[2]; As[c4 + 3][r] = vv[3];
        }
        #pragma unroll
        for (int p = 0; p < 4; p++){
            int f = p * 256 + tid;
            int j = f >> 3;
            int c4 = (f & 7) * 4;
            float4 v = *reinterpret_cast<const float4*>(&Bw[(size_t)j * ldb + kk + c4]);
            Bs[c4 + 0][j] = v.x; Bs[c4 + 1][j] = v.y; Bs[c4 + 2][j] = v.z; Bs[c4 + 3][j] = v.w;
        }
        __syncthreads();
        #pragma unroll
        for (int k = 0; k < BK; k++){
            float a[8], b[8];
            #pragma unroll
            for (int i = 0; i < 8; i++) a[i] = As[k][ty * 8 + i];
            #pragma unroll
            for (int j = 0; j < 8; j++) b[j] = Bs[k][tx * 8 + j];
            #pragma unroll
            for (int i = 0; i < 8; i++)
                #pragma unroll
                for (int j = 0; j < 8; j++)
                    acc[i][j] = fmaf(a[i], b[j], acc[i][j]);
        }
    }
    #pragma unroll
    for (int i = 0; i < 8; i++){
        int row = m0 + ty * 8 + i;
        if (row < N){
            #pragma unroll
            for (int j = 0; j < 8; j++){
                int col = tx * 8 + j;
                size_t idx = (size_t)row * 128 + col;
                float base = first ? b2l[col] : Cz2[idx];
                Cz2[idx] = base + acc[i][j];
            }
        }
    }
}

// ---------------- GraphNorm stats (batch sorted) ----------------
__global__ void gn_stats_kernel(const float* __restrict__ z2, const int* __restrict__ batch,
                                float* __restrict__ gsum, float* __restrict__ gsq, int N){
    __shared__ int sb[128];
    int c = threadIdx.x;
    int base = blockIdx.x * 128;
    int end = min(128, N - base);
    if (c < end) sb[c] = batch[base + c];
    __syncthreads();
    float s = 0.f, q = 0.f;
    int run_g = sb[0];
    for (int r = 0; r < end; r++){
        int g = sb[r];
        if (g != run_g){
            atomicAdd(&gsum[run_g * 128 + c], s);
            atomicAdd(&gsq[run_g * 128 + c], q);
            s = 0.f; q = 0.f; run_g = g;
        }
        float v = z2[(size_t)(base + r) * 128 + c];
        s += v; q += v * v;
    }
    atomicAdd(&gsum[run_g * 128 + c], s);
    atomicAdd(&gsq[run_g * 128 + c], q);
}

__global__ void gn_final_kernel(float* __restrict__ gsum, float* __restrict__ gsq,
                                const float* __restrict__ cnt,
                                const float* __restrict__ gng, const float* __restrict__ gnb,
                                const float* __restrict__ gna,
                                float* __restrict__ scale, float* __restrict__ shift, int l){
    int g = blockIdx.x, c = threadIdx.x;
    int idx = g * 128 + c;
    float n = cnt[g];
    float m = gsum[idx] / n;
    float e2 = gsq[idx] / n;
    float a = gna[l * 128 + c];
    float var = e2 - (2.f * a - a * a) * m * m;
    float inv = rsqrtf(var + 1e-5f);
    float sc = gng[l * 128 + c] * inv;
    scale[idx] = sc;
    shift[idx] = gnb[l * 128 + c] - a * m * sc;
    gsum[idx] = 0.f;
    gsq[idx] = 0.f;
}

// ------- apply GraphNorm + SELU in place (z2 -> h), accumulate pooled sums -------
__global__ void gn_apply_kernel(float* __restrict__ z2h, const int* __restrict__ batch,
                                const float* __restrict__ scale, const float* __restrict__ shift,
                                float* __restrict__ pool, int l, int N){
    __shared__ int sb[128];
    int c = threadIdx.x;
    int base = blockIdx.x * 128;
    int end = min(128, N - base);
    if (c < end) sb[c] = batch[base + c];
    __syncthreads();
    int run_g = sb[0];
    float sc = scale[run_g * 128 + c], sh = shift[run_g * 128 + c];
    float psum = 0.f;
    for (int r = 0; r < end; r++){
        int g = sb[r];
        if (g != run_g){
            atomicAdd(&pool[run_g * 512 + l * 128 + c], psum);
            psum = 0.f; run_g = g;
            sc = scale[g * 128 + c]; sh = shift[g * 128 + c];
        }
        size_t idx = (size_t)(base + r) * 128 + c;
        float v = fmaf(z2h[idx], sc, sh);
        v = selu_f(v);
        z2h[idx] = v;
        psum += v;
    }
    atomicAdd(&pool[run_g * 512 + l * 128 + c], psum);
}

__global__ void final_kernel(const float* __restrict__ pool, const float* __restrict__ cnt,
                             float* __restrict__ out, int n){
    int i = blockIdx.x * 256 + threadIdx.x;
    if (i < n) out[i] = pool[i] / cnt[i >> 9];
}

extern "C" void kernel_launch(void* const* d_in, const int* in_sizes, int n_in,
                              void* d_out, int out_size, void* d_ws, size_t ws_size,
                              hipStream_t stream){
    const float* x    = (const float*)d_in[0];
    const float* W1   = (const float*)d_in[1];
    const float* bng  = (const float*)d_in[2];
    const float* bnb  = (const float*)d_in[3];
    const float* W2   = (const float*)d_in[4];
    const float* b2   = (const float*)d_in[5];
    const float* gng  = (const float*)d_in[6];
    const float* gnb  = (const float*)d_in[7];
    const float* gna  = (const float*)d_in[8];
    const int*   ei   = (const int*)d_in[9];
    const int*   batch= (const int*)d_in[10];
    int N = in_sizes[0] / 128;
    int E = in_sizes[9] / 2;
    float* out = (float*)d_out;

    char* ws = (char*)d_ws;
    size_t off = 0;
    auto alloc = [&](size_t bytes) -> char* {
        char* p = ws + off;
        off += (bytes + 255) & ~(size_t)255;
        return p;
    };
    float* z0     = (float*)alloc((size_t)N * 128 * 4);
    float* chunk  = (float*)alloc((size_t)N * 128 * 4);
    float* z2     = (float*)alloc((size_t)N * 128 * 4);   // doubles as h after gn_apply
    int*   row_ptr= (int*)alloc((size_t)(N + 1) * 4);
    int*   colv   = (int*)alloc((size_t)E * 4);
    int*   counts = (int*)alloc((size_t)N * 4);
    int*   fill   = (int*)alloc((size_t)N * 4);
    int*   gcount = (int*)alloc(256 * 4);
    float* cnt_f  = (float*)alloc(256 * 4);
    float* bn_sum = (float*)alloc(128 * 4);   // contiguous with bn_sq (512B aligned block)
    float* bn_sq  = (float*)alloc(128 * 4);
    float* bn_sc  = (float*)alloc(128 * 4);
    float* bn_sh  = (float*)alloc(128 * 4);
    float* gn_sum = (float*)alloc(256 * 128 * 4);  // contiguous with gn_sq
    float* gn_sq  = (float*)alloc(256 * 128 * 4);
    float* gn_sc  = (float*)alloc(256 * 128 * 4);
    float* gn_sh  = (float*)alloc(256 * 128 * 4);
    float* pool   = (float*)alloc(256 * 512 * 4);
    (void)ws_size;

    hipMemsetAsync(counts, 0, (size_t)N * 4, stream);
    hipMemsetAsync(fill,   0, (size_t)N * 4, stream);
    hipMemsetAsync(gcount, 0, 256 * 4, stream);
    hipMemsetAsync(bn_sum, 0, 2 * 128 * 4, stream);            // bn_sum + bn_sq
    hipMemsetAsync(gn_sum, 0, 2 * 256 * 128 * 4, stream);      // gn_sum + gn_sq
    hipMemsetAsync(pool,   0, 256 * 512 * 4, stream);

    count_kernel<<<(E + 255) / 256, 256, 0, stream>>>(ei + E, counts, E);
    gcount_kernel<<<(N + 255) / 256, 256, 0, stream>>>(batch, gcount, N);
    scan_kernel<<<1, 1024, 0, stream>>>(counts, row_ptr, N);
    fill_kernel<<<(E + 255) / 256, 256, 0, stream>>>(ei, row_ptr, fill, colv, E);
    cnt_final_kernel<<<1, 256, 0, stream>>>(gcount, cnt_f);

    int RB = (N + 127) / 128;
    const float* hcur = x;
    for (int l = 0; l < 4; l++){
        agg_kernel<<<N, 128, 0, stream>>>(hcur, row_ptr, colv, z0, N);
        for (int c = 0; c < 4; c++){
            const float* B1 = W1 + (size_t)l * 512 * 128 + (size_t)c * 128 * 128;
            gemm1_kernel<<<RB, WG_GEMM, 0, stream>>>(z0, B1, chunk, N);
            bn_stats_kernel<<<RB, 128, 0, stream>>>(chunk, bn_sum, bn_sq, N);
            bn_final_kernel<<<1, 128, 0, stream>>>(bn_sum, bn_sq, bng, bnb, bn_sc, bn_sh,
                                                   l, c * 128, N);
            const float* B2 = W2 + (size_t)l * 128 * 512 + (size_t)c * 128;
            gemm2_kernel<<<RB, WG_GEMM, 0, stream>>>(chunk, B2, 512, z2, bn_sc, bn_sh,
                                                     b2 + l * 128, (c == 0) ? 1 : 0, N);
        }
        gn_stats_kernel<<<RB, 128, 0, stream>>>(z2, batch, gn_sum, gn_sq, N);
        gn_final_kernel<<<256, 128, 0, stream>>>(gn_sum, gn_sq, cnt_f, gng, gnb, gna,
                                                 gn_sc, gn_sh, l);
        gn_apply_kernel<<<RB, 128, 0, stream>>>(z2, batch, gn_sc, gn_sh, pool, l, N);
        hcur = z2;
    }
    final_kernel<<<(out_size + 255) / 256, 256, 0, stream>>>(pool, cnt_f, out, out_size);
}